// Round 5
// baseline (2323.354 us; speedup 1.0000x reference)
//
#include <hip/hip_runtime.h>
#include <cstdint>
#include <math.h>

#define T_TOK 8192
#define DM 1024
#define DFF 4096
#define NE 8

typedef __attribute__((ext_vector_type(8))) short short8;
typedef __attribute__((ext_vector_type(4))) float f32x4;

#define GLDS16(g, l) __builtin_amdgcn_global_load_lds( \
    (const __attribute__((address_space(1))) void*)(g), \
    (__attribute__((address_space(3))) void*)(l), 16, 0, 0)

static __device__ __forceinline__ unsigned short f2bf(float f) {
    union { float f; unsigned int u; } v; v.f = f;
    unsigned int r = (v.u + 0x7FFFu + ((v.u >> 16) & 1u)) >> 16;
    return (unsigned short)r;
}

// ---------------- fp32 -> bf16 converters ----------------
__global__ __launch_bounds__(256) void conv_flat(const float* __restrict__ src,
                                                 unsigned short* __restrict__ dst,
                                                 long long n)
{
    long long i = ((long long)blockIdx.x * 256 + threadIdx.x) * 4;
    if (i >= n) return;
    const float4 v = *(const float4*)(src + i);
    uint2 u;
    u.x = (unsigned)f2bf(v.x) | ((unsigned)f2bf(v.y) << 16);
    u.y = (unsigned)f2bf(v.z) | ((unsigned)f2bf(v.w) << 16);
    *(uint2*)(dst + i) = u;
}

__global__ __launch_bounds__(256) void conv_rows(const float* __restrict__ src,
                                                 unsigned short* __restrict__ dst,
                                                 long long src_off, long long src_stride,
                                                 int ncols)
{
    long long row = blockIdx.y;
    int c = (blockIdx.x * 256 + threadIdx.x) * 4;
    if (c >= ncols) return;
    const float4 v = *(const float4*)(src + src_off + row * src_stride + c);
    uint2 u;
    u.x = (unsigned)f2bf(v.x) | ((unsigned)f2bf(v.y) << 16);
    u.y = (unsigned)f2bf(v.z) | ((unsigned)f2bf(v.w) << 16);
    *(uint2*)(dst + row * (long long)ncols + c) = u;
}

// ---------------- Router ----------------
__global__ __launch_bounds__(256) void router_kernel(
    const float* __restrict__ x, const float* __restrict__ gw,
    int* __restrict__ counts, float* __restrict__ imp,
    int* __restrict__ ptok, float* __restrict__ pw)
{
    __shared__ float4 sgw[NE * 256];
    __shared__ float simp[NE];
    const int tid = threadIdx.x;
    #pragma unroll
    for (int j = 0; j < 8; ++j) sgw[tid + j * 256] = ((const float4*)gw)[tid + j * 256];
    if (tid < NE) simp[tid] = 0.f;
    __syncthreads();

    const int wid = tid >> 6, lane = tid & 63;
    const int t = blockIdx.x * 4 + wid;
    float acc[NE];
    #pragma unroll
    for (int e = 0; e < NE; ++e) acc[e] = 0.f;
    const float4* xr = (const float4*)(x + (size_t)t * DM);
    #pragma unroll
    for (int j = 0; j < 4; ++j) {
        int idx = lane + j * 64;
        float4 xv = xr[idx];
        #pragma unroll
        for (int e = 0; e < NE; ++e) {
            float4 g = sgw[e * 256 + idx];
            acc[e] += xv.x * g.x + xv.y * g.y + xv.z * g.z + xv.w * g.w;
        }
    }
    #pragma unroll
    for (int off = 32; off; off >>= 1) {
        #pragma unroll
        for (int e = 0; e < NE; ++e) acc[e] += __shfl_xor(acc[e], off);
    }
    if (lane == 0) {
        float m = acc[0];
        #pragma unroll
        for (int e = 1; e < NE; ++e) m = fmaxf(m, acc[e]);
        float p[NE], s = 0.f;
        #pragma unroll
        for (int e = 0; e < NE; ++e) { p[e] = expf(acc[e] - m); s += p[e]; }
        float inv = 1.f / s;
        #pragma unroll
        for (int e = 0; e < NE; ++e) { p[e] *= inv; atomicAdd(&simp[e], p[e]); }
        int i0 = 0;
        #pragma unroll
        for (int e = 1; e < NE; ++e) if (p[e] > p[i0]) i0 = e;
        int i1 = (i0 == 0) ? 1 : 0;
        #pragma unroll
        for (int e = 0; e < NE; ++e) if (e != i0 && p[e] > p[i1]) i1 = e;
        float v0 = p[i0], v1 = p[i1], wsum = v0 + v1;
        int s0 = atomicAdd(&counts[i0], 1);
        ptok[i0 * T_TOK + s0] = t; pw[i0 * T_TOK + s0] = v0 / wsum;
        int s1 = atomicAdd(&counts[i1], 1);
        ptok[i1 * T_TOK + s1] = t; pw[i1 * T_TOK + s1] = v1 / wsum;
    }
    __syncthreads();
    if (tid < NE) atomicAdd(&imp[tid], simp[tid]);
}

__global__ void finalize_kernel(const int* __restrict__ counts,
                                const float* __restrict__ imp,
                                int* __restrict__ offs, float* __restrict__ aux_out)
{
    if (threadIdx.x == 0 && blockIdx.x == 0) {
        int o = 0; float aux = 0.f;
        for (int e = 0; e < NE; ++e) {
            offs[e] = o; o += counts[e];
            aux += (imp[e] / (float)T_TOK) * ((float)counts[e] / (float)(T_TOK * 2));
        }
        offs[NE] = o;
        *aux_out = (float)NE * aux;
    }
}

// swizzled 16B-slot byte index within a 64B LDS row (as shorts offset)
#define SWZ(row, sl) ((((sl) ^ (((row) + ((row) >> 2)) & 3)) * 8))

// ---------------- Grouped GEMM (B^T), 256x256 tile, BK=32, 8 waves, dbuf + swizzle ----------------
// EPI==0: H[pair, f] = gelu(gather(xb) @ w1b[e]^T + b1)   (K = DM,  N = FFC chunk)
// EPI==1: out[tok,d] += w_pair * (H @ w2b[e]^T + b2)      (K = FFC, N = DM)
template<int EPI>
__global__ __launch_bounds__(512, 2) void gemm_bt(
    const unsigned short* __restrict__ A,
    const unsigned short* __restrict__ W,
    const float* __restrict__ bias,
    const int* __restrict__ counts, const int* __restrict__ offs,
    const int* __restrict__ ptok, const float* __restrict__ pw,
    unsigned short* __restrict__ Hout, float* __restrict__ out,
    int FFC, int cch, int wfull)
{
    const int e = blockIdx.z;
    const int n_e = counts[e];
    const int m0 = blockIdx.x * 256;
    if (m0 >= n_e) return;
    const int nt = blockIdx.y;
    const int KD = (EPI == 0) ? DM : FFC;
    const int hbase = offs[e];

    __shared__ unsigned short lA[2][256 * 32];   // 16 KB x2
    __shared__ unsigned short lB[2][256 * 32];   // 16 KB x2  -> 64 KB total

    const int tid = threadIdx.x, lane = tid & 63, wid = tid >> 6;
    const int wr = wid >> 2, wc = wid & 3;       // 2M x 4N wave grid
    const int lo = lane & 15, hi = lane >> 4;

    int wrow0; long long wstride, wcol0;
    if (EPI == 0) {
        wrow0 = e * (wfull ? DFF : FFC) + (wfull ? cch * FFC : 0) + nt * 256;
        wstride = DM; wcol0 = 0;
    } else {
        wrow0 = e * DM + nt * 256;
        wstride = (wfull ? DFF : FFC); wcol0 = (wfull ? (long long)cch * FFC : 0);
    }

    // staging source addresses (2 A-slots + 2 B-slots per thread, 16B each),
    // column pre-swizzled (inverse of read swizzle) so linear LDS dest works (rule #21)
    const unsigned short* aaddr[2];
    const unsigned short* baddr[2];
    #pragma unroll
    for (int j = 0; j < 2; ++j) {
        int li = tid + j * 512;
        int r = li >> 2, s = li & 3;
        int scol = (s ^ ((r + (r >> 2)) & 3)) * 8;
        long long arow;
        int m = m0 + r;
        if (EPI == 0) {
            int tok = ptok[e * T_TOK + (m < n_e ? m : 0)];
            arow = (long long)tok * DM;
        } else {
            arow = (long long)(hbase + (m < n_e ? m : 0)) * FFC;
        }
        aaddr[j] = A + arow + scol;
        baddr[j] = W + (long long)(wrow0 + r) * wstride + wcol0 + scol;
    }

    f32x4 acc[8][4];
    #pragma unroll
    for (int i = 0; i < 8; ++i)
        #pragma unroll
        for (int j = 0; j < 4; ++j) acc[i][j] = (f32x4)0.f;

    const int NT = KD / 32;

    // prologue: stage K-tile 0 into buf 0
    #pragma unroll
    for (int j = 0; j < 2; ++j) {
        GLDS16(aaddr[j], &lA[0][(tid + j * 512) * 8]);
        GLDS16(baddr[j], &lB[0][(tid + j * 512) * 8]);
    }
    __syncthreads();

    for (int t = 0; t < NT; ++t) {
        const int cur = t & 1;
        if (t + 1 < NT) {
            const int nxt = cur ^ 1;
            const long long k0 = (long long)(t + 1) * 32;
            #pragma unroll
            for (int j = 0; j < 2; ++j) {
                GLDS16(aaddr[j] + k0, &lA[nxt][(tid + j * 512) * 8]);
                GLDS16(baddr[j] + k0, &lB[nxt][(tid + j * 512) * 8]);
            }
        }
        short8 af[8], bf[4];
        #pragma unroll
        for (int mi = 0; mi < 8; ++mi) {
            int row = wr * 128 + mi * 16 + lo;
            af[mi] = *(const short8*)(&lA[cur][row * 32 + SWZ(row, hi)]);
        }
        #pragma unroll
        for (int nj = 0; nj < 4; ++nj) {
            int row = wc * 64 + nj * 16 + lo;
            bf[nj] = *(const short8*)(&lB[cur][row * 32 + SWZ(row, hi)]);
        }
        #pragma unroll
        for (int mi = 0; mi < 8; ++mi)
            #pragma unroll
            for (int nj = 0; nj < 4; ++nj)
                acc[mi][nj] = __builtin_amdgcn_mfma_f32_16x16x32_bf16(af[mi], bf[nj], acc[mi][nj], 0, 0, 0);
        __syncthreads();
    }

    // ---- epilogue: wave writes its 128x64 sub-tile ----
    const int rbase = hi * 4;
    if (EPI == 0) {
        #pragma unroll
        for (int mi = 0; mi < 8; ++mi) {
            #pragma unroll
            for (int r = 0; r < 4; ++r) {
                int m = m0 + wr * 128 + mi * 16 + rbase + r;
                if (m >= n_e) continue;
                long long hrow = (long long)(hbase + m) * FFC;
                #pragma unroll
                for (int nj = 0; nj < 4; ++nj) {
                    int f = nt * 256 + wc * 64 + nj * 16 + lo;
                    float v = acc[mi][nj][r] + bias[e * DFF + cch * FFC + f];
                    float g = 0.5f * v * (1.f + erff(v * 0.70710678118654752f));
                    Hout[hrow + f] = f2bf(g);
                }
            }
        }
    } else {
        #pragma unroll
        for (int mi = 0; mi < 8; ++mi) {
            #pragma unroll
            for (int r = 0; r < 4; ++r) {
                int m = m0 + wr * 128 + mi * 16 + rbase + r;
                if (m >= n_e) continue;
                int pidx = e * T_TOK + m;
                int tok = ptok[pidx];
                float wgt = pw[pidx];
                float* orow = out + (long long)tok * DM;
                #pragma unroll
                for (int nj = 0; nj < 4; ++nj) {
                    int d = nt * 256 + wc * 64 + nj * 16 + lo;
                    float v = acc[mi][nj][r];
                    if (cch == 0) v += bias[e * DM + d];
                    atomicAdd(&orow[d], wgt * v);
                }
            }
        }
    }
}

extern "C" void kernel_launch(void* const* d_in, const int* in_sizes, int n_in,
                              void* d_out, int out_size, void* d_ws, size_t ws_size,
                              hipStream_t stream)
{
    const float* x  = (const float*)d_in[0];
    const float* gw = (const float*)d_in[1];
    const float* w1 = (const float*)d_in[2];
    const float* b1 = (const float*)d_in[3];
    const float* w2 = (const float*)d_in[4];
    const float* b2 = (const float*)d_in[5];
    float* out = (float*)d_out;

    char* ws = (char*)d_ws;
    int*   counts = (int*)ws;
    float* imp    = (float*)(ws + 64);
    int*   offs   = (int*)(ws + 128);
    int*   ptok   = (int*)(ws + 256);
    float* pw     = (float*)(ws + 256 + (size_t)NE * T_TOK * 4);
    size_t cur = 256 + (size_t)NE * T_TOK * 8;
    cur = (cur + 511) & ~(size_t)511;

    unsigned short* xb = (unsigned short*)(ws + cur);
    cur += (size_t)T_TOK * DM * 2;

    const size_t wfull_bytes = (size_t)NE * DFF * DM * 2;
    const size_t hrow_total  = 2 * (size_t)T_TOK;

    int FFC = 0, wfull = 0;
    unsigned short *w1b = nullptr, *w2b = nullptr, *H = nullptr;
    for (int f = DFF; f >= 512; f >>= 1) {
        size_t need = cur + 2 * wfull_bytes + hrow_total * (size_t)f * 2;
        if (need <= ws_size) { FFC = f; wfull = 1; break; }
    }
    if (wfull) {
        w1b = (unsigned short*)(ws + cur); cur += wfull_bytes;
        w2b = (unsigned short*)(ws + cur); cur += wfull_bytes;
        H   = (unsigned short*)(ws + cur);
    } else {
        for (int f = 1024; f >= 256; f >>= 1) {
            size_t wc = (size_t)NE * f * DM * 2;
            size_t need = cur + 2 * wc + hrow_total * (size_t)f * 2;
            if (need <= ws_size) { FFC = f; break; }
        }
        if (FFC == 0) return;
        size_t wc = (size_t)NE * FFC * DM * 2;
        w1b = (unsigned short*)(ws + cur); cur += wc;
        w2b = (unsigned short*)(ws + cur); cur += wc;
        H   = (unsigned short*)(ws + cur);
    }

    hipMemsetAsync(ws, 0, 256, stream);
    hipMemsetAsync(d_out, 0, (size_t)out_size * 4, stream);

    router_kernel<<<T_TOK / 4, 256, 0, stream>>>(x, gw, counts, imp, ptok, pw);
    finalize_kernel<<<1, 64, 0, stream>>>(counts, imp, offs, out + (size_t)out_size - 1);

    {
        long long n = (long long)T_TOK * DM;
        conv_flat<<<(unsigned)(n / 1024), 256, 0, stream>>>(x, xb, n);
    }
    if (wfull) {
        long long n = (long long)NE * DFF * DM;
        conv_flat<<<(unsigned)(n / 1024), 256, 0, stream>>>(w1, w1b, n);
        conv_flat<<<(unsigned)(n / 1024), 256, 0, stream>>>(w2, w2b, n);
    }

    const int NCH = DFF / FFC;
    for (int c = 0; c < NCH; ++c) {
        if (!wfull) {
            dim3 gc1((unsigned)((long long)FFC * DM / 1024), NE);
            conv_rows<<<gc1, 256, 0, stream>>>(w1, w1b,
                (long long)c * FFC * DM, (long long)DFF * DM, FFC * DM);
            dim3 gc2((unsigned)((FFC + 1023) / 1024), NE * DM);
            conv_rows<<<gc2, 256, 0, stream>>>(w2, w2b,
                (long long)c * FFC, (long long)DFF, FFC);
        }
        dim3 g1(T_TOK / 256, FFC / 256, NE);
        gemm_bt<0><<<g1, 512, 0, stream>>>(xb, w1b, b1, counts, offs, ptok, pw, H, out, FFC, c, wfull);
        dim3 g2(T_TOK / 256, DM / 256, NE);
        gemm_bt<1><<<g2, 512, 0, stream>>>(H, w2b, b2, counts, offs, ptok, pw, H, out, FFC, c, wfull);
    }
}

// Round 6
// 2169.217 us; speedup vs baseline: 1.0711x; 1.0711x over previous
//
#include <hip/hip_runtime.h>
#include <cstdint>
#include <math.h>

#define T_TOK 8192
#define DM 1024
#define DFF 4096
#define NE 8

typedef __attribute__((ext_vector_type(8))) short short8;
typedef __attribute__((ext_vector_type(4))) float f32x4;

#define GLDS16(g, l) __builtin_amdgcn_global_load_lds( \
    (const __attribute__((address_space(1))) void*)(g), \
    (__attribute__((address_space(3))) void*)(l), 16, 0, 0)

static __device__ __forceinline__ unsigned short f2bf(float f) {
    union { float f; unsigned int u; } v; v.f = f;
    unsigned int r = (v.u + 0x7FFFu + ((v.u >> 16) & 1u)) >> 16;
    return (unsigned short)r;
}

// ---------------- fp32 -> bf16 converters ----------------
__global__ __launch_bounds__(256) void conv_flat(const float* __restrict__ src,
                                                 unsigned short* __restrict__ dst,
                                                 long long n)
{
    long long i = ((long long)blockIdx.x * 256 + threadIdx.x) * 4;
    if (i >= n) return;
    const float4 v = *(const float4*)(src + i);
    uint2 u;
    u.x = (unsigned)f2bf(v.x) | ((unsigned)f2bf(v.y) << 16);
    u.y = (unsigned)f2bf(v.z) | ((unsigned)f2bf(v.w) << 16);
    *(uint2*)(dst + i) = u;
}

__global__ __launch_bounds__(256) void conv_rows(const float* __restrict__ src,
                                                 unsigned short* __restrict__ dst,
                                                 long long src_off, long long src_stride,
                                                 int ncols)
{
    long long row = blockIdx.y;
    int c = (blockIdx.x * 256 + threadIdx.x) * 4;
    if (c >= ncols) return;
    const float4 v = *(const float4*)(src + src_off + row * src_stride + c);
    uint2 u;
    u.x = (unsigned)f2bf(v.x) | ((unsigned)f2bf(v.y) << 16);
    u.y = (unsigned)f2bf(v.z) | ((unsigned)f2bf(v.w) << 16);
    *(uint2*)(dst + row * (long long)ncols + c) = u;
}

// ---------------- Router ----------------
__global__ __launch_bounds__(256) void router_kernel(
    const float* __restrict__ x, const float* __restrict__ gw,
    int* __restrict__ counts, float* __restrict__ imp,
    int* __restrict__ ptok, float* __restrict__ pw)
{
    __shared__ float4 sgw[NE * 256];
    __shared__ float simp[NE];
    const int tid = threadIdx.x;
    #pragma unroll
    for (int j = 0; j < 8; ++j) sgw[tid + j * 256] = ((const float4*)gw)[tid + j * 256];
    if (tid < NE) simp[tid] = 0.f;
    __syncthreads();

    const int wid = tid >> 6, lane = tid & 63;
    const int t = blockIdx.x * 4 + wid;
    float acc[NE];
    #pragma unroll
    for (int e = 0; e < NE; ++e) acc[e] = 0.f;
    const float4* xr = (const float4*)(x + (size_t)t * DM);
    #pragma unroll
    for (int j = 0; j < 4; ++j) {
        int idx = lane + j * 64;
        float4 xv = xr[idx];
        #pragma unroll
        for (int e = 0; e < NE; ++e) {
            float4 g = sgw[e * 256 + idx];
            acc[e] += xv.x * g.x + xv.y * g.y + xv.z * g.z + xv.w * g.w;
        }
    }
    #pragma unroll
    for (int off = 32; off; off >>= 1) {
        #pragma unroll
        for (int e = 0; e < NE; ++e) acc[e] += __shfl_xor(acc[e], off);
    }
    if (lane == 0) {
        float m = acc[0];
        #pragma unroll
        for (int e = 1; e < NE; ++e) m = fmaxf(m, acc[e]);
        float p[NE], s = 0.f;
        #pragma unroll
        for (int e = 0; e < NE; ++e) { p[e] = expf(acc[e] - m); s += p[e]; }
        float inv = 1.f / s;
        #pragma unroll
        for (int e = 0; e < NE; ++e) { p[e] *= inv; atomicAdd(&simp[e], p[e]); }
        int i0 = 0;
        #pragma unroll
        for (int e = 1; e < NE; ++e) if (p[e] > p[i0]) i0 = e;
        int i1 = (i0 == 0) ? 1 : 0;
        #pragma unroll
        for (int e = 0; e < NE; ++e) if (e != i0 && p[e] > p[i1]) i1 = e;
        float v0 = p[i0], v1 = p[i1], wsum = v0 + v1;
        int s0 = atomicAdd(&counts[i0], 1);
        ptok[i0 * T_TOK + s0] = t; pw[i0 * T_TOK + s0] = v0 / wsum;
        int s1 = atomicAdd(&counts[i1], 1);
        ptok[i1 * T_TOK + s1] = t; pw[i1 * T_TOK + s1] = v1 / wsum;
    }
    __syncthreads();
    if (tid < NE) atomicAdd(&imp[tid], simp[tid]);
}

__global__ void finalize_kernel(const int* __restrict__ counts,
                                const float* __restrict__ imp,
                                int* __restrict__ offs, float* __restrict__ aux_out)
{
    if (threadIdx.x == 0 && blockIdx.x == 0) {
        int o = 0; float aux = 0.f;
        for (int e = 0; e < NE; ++e) {
            offs[e] = o; o += counts[e];
            aux += (imp[e] / (float)T_TOK) * ((float)counts[e] / (float)(T_TOK * 2));
        }
        offs[NE] = o;
        *aux_out = (float)NE * aux;
    }
}

// ---------------- Grouped GEMM (B^T), 128x128, BK=64, 3-deep pipeline + counted vmcnt ----------------
// EPI==0: H[pair, f] = gelu(gather(xb) @ w1b[e]^T + b1)   (K = DM,  N = FFC chunk)
// EPI==1: out[tok,d] += w_pair * (H @ w2b[e]^T + b2)      (K = FFC, N = DM)
template<int EPI>
__global__ __launch_bounds__(256) void gemm_bt(
    const unsigned short* __restrict__ A,
    const unsigned short* __restrict__ W,
    const float* __restrict__ bias,
    const int* __restrict__ counts, const int* __restrict__ offs,
    const int* __restrict__ ptok, const float* __restrict__ pw,
    unsigned short* __restrict__ Hout, float* __restrict__ out,
    int FFC, int cch, int wfull)
{
    const int e = blockIdx.z;
    const int n_e = counts[e];
    const int m0 = blockIdx.x * 128;
    if (m0 >= n_e) return;
    const int nt = blockIdx.y;
    const int KD = (EPI == 0) ? DM : FFC;
    const int hbase = offs[e];

    // 3-deep pipelined LDS: 3 x (16KB A + 16KB B) = 96 KB
    __shared__ unsigned short lA[3][128 * 64];
    __shared__ unsigned short lB[3][128 * 64];

    const int tid = threadIdx.x, lane = tid & 63, wid = tid >> 6;
    const int msub = (wid & 1) * 64, nsub = (wid >> 1) * 64;
    const int hi = lane >> 4, lo = lane & 15;

    int wrow0; long long wstride, wcol0;
    if (EPI == 0) {
        wrow0 = e * (wfull ? DFF : FFC) + (wfull ? cch * FFC : 0) + nt * 128;
        wstride = DM; wcol0 = 0;
    } else {
        wrow0 = e * DM + nt * 128;
        wstride = (wfull ? DFF : FFC); wcol0 = (wfull ? (long long)cch * FFC : 0);
    }

    // Per-thread global source addresses, column pre-swizzled (inverse of read
    // swizzle) so linear global_load_lds dest + XOR'd ds_read = identity (rule #21).
    // Verified: round-3 bench, SQ_LDS_BANK_CONFLICT == 0.
    const unsigned short* aaddr[4];
    const unsigned short* baddr[4];
    #pragma unroll
    for (int j = 0; j < 4; ++j) {
        int li = tid + j * 256;
        int r = li >> 3;
        int scol = ((li & 7) ^ (r & 7)) * 8;   // swizzled 16B slot within 128B row
        long long arow;
        int m = m0 + r;
        if (EPI == 0) {
            int tok = ptok[e * T_TOK + (m < n_e ? m : 0)];
            arow = (long long)tok * DM;
        } else {
            arow = (long long)(hbase + (m < n_e ? m : 0)) * FFC;
        }
        aaddr[j] = A + arow + scol;
        baddr[j] = W + (long long)(wrow0 + r) * wstride + wcol0 + scol;
    }

    f32x4 acc[4][4];
    #pragma unroll
    for (int i = 0; i < 4; ++i)
        #pragma unroll
        for (int j = 0; j < 4; ++j) acc[i][j] = (f32x4)0.f;

    const int NT = KD / 64;   // >= 8 always

    // prologue: stage tiles 0,1,2 into buffers 0,1,2 (24 loads/thread in flight)
    #pragma unroll
    for (int p = 0; p < 3; ++p) {
        const long long k0 = (long long)p * 64;
        #pragma unroll
        for (int j = 0; j < 4; ++j) {
            GLDS16(aaddr[j] + k0, &lA[p][(tid + j * 256) * 8]);
            GLDS16(baddr[j] + k0, &lB[p][(tid + j * 256) * 8]);
        }
    }

    int cs = 0;  // rotating buffer slot for tile t
    for (int t = 0; t < NT; ++t) {
        // counted vmcnt: retire ONLY tile t's 8 loads; t+1, t+2 stay in flight
        if (t + 2 < NT)      asm volatile("s_waitcnt vmcnt(16)" ::: "memory");
        else if (t + 1 < NT) asm volatile("s_waitcnt vmcnt(8)" ::: "memory");
        else                 asm volatile("s_waitcnt vmcnt(0)" ::: "memory");
        __builtin_amdgcn_s_barrier();          // all waves: tile t data visible
        asm volatile("" ::: "memory");

        #pragma unroll
        for (int kk = 0; kk < 2; ++kk) {
            const int soff = ((kk * 4 + hi) ^ (lo & 7)) * 8;  // swizzled read slot
            short8 af[4], bf[4];
            #pragma unroll
            for (int i = 0; i < 4; ++i) {
                af[i] = *(const short8*)(&lA[cs][(msub + i * 16 + lo) * 64 + soff]);
                bf[i] = *(const short8*)(&lB[cs][(nsub + i * 16 + lo) * 64 + soff]);
            }
            #pragma unroll
            for (int mi = 0; mi < 4; ++mi)
                #pragma unroll
                for (int nj = 0; nj < 4; ++nj)
                    acc[mi][nj] = __builtin_amdgcn_mfma_f32_16x16x32_bf16(af[mi], bf[nj], acc[mi][nj], 0, 0, 0);
        }

        asm volatile("" ::: "memory");
        __builtin_amdgcn_s_barrier();          // all waves done reading buf cs

        if (t + 3 < NT) {                       // refill freed buffer with tile t+3
            const long long k0 = (long long)(t + 3) * 64;
            #pragma unroll
            for (int j = 0; j < 4; ++j) {
                GLDS16(aaddr[j] + k0, &lA[cs][(tid + j * 256) * 8]);
                GLDS16(baddr[j] + k0, &lB[cs][(tid + j * 256) * 8]);
            }
        }
        cs = (cs == 2) ? 0 : cs + 1;
    }

    // ---- epilogue ----
    const int rbase = hi * 4, cidx = lo;
    if (EPI == 0) {
        #pragma unroll
        for (int mi = 0; mi < 4; ++mi) {
            #pragma unroll
            for (int r = 0; r < 4; ++r) {
                int m = m0 + msub + mi * 16 + rbase + r;
                if (m >= n_e) continue;
                long long hrow = (long long)(hbase + m) * FFC;
                #pragma unroll
                for (int nj = 0; nj < 4; ++nj) {
                    int f = nt * 128 + nsub + nj * 16 + cidx;
                    float v = acc[mi][nj][r] + bias[e * DFF + cch * FFC + f];
                    float g = 0.5f * v * (1.f + erff(v * 0.70710678118654752f));
                    Hout[hrow + f] = f2bf(g);
                }
            }
        }
    } else {
        #pragma unroll
        for (int mi = 0; mi < 4; ++mi) {
            #pragma unroll
            for (int r = 0; r < 4; ++r) {
                int m = m0 + msub + mi * 16 + rbase + r;
                if (m >= n_e) continue;
                int pidx = e * T_TOK + m;
                int tok = ptok[pidx];
                float wgt = pw[pidx];
                float* orow = out + (long long)tok * DM;
                #pragma unroll
                for (int nj = 0; nj < 4; ++nj) {
                    int d = nt * 128 + nsub + nj * 16 + cidx;
                    float v = acc[mi][nj][r];
                    if (cch == 0) v += bias[e * DM + d];
                    atomicAdd(&orow[d], wgt * v);
                }
            }
        }
    }
}

extern "C" void kernel_launch(void* const* d_in, const int* in_sizes, int n_in,
                              void* d_out, int out_size, void* d_ws, size_t ws_size,
                              hipStream_t stream)
{
    const float* x  = (const float*)d_in[0];
    const float* gw = (const float*)d_in[1];
    const float* w1 = (const float*)d_in[2];
    const float* b1 = (const float*)d_in[3];
    const float* w2 = (const float*)d_in[4];
    const float* b2 = (const float*)d_in[5];
    float* out = (float*)d_out;

    char* ws = (char*)d_ws;
    int*   counts = (int*)ws;
    float* imp    = (float*)(ws + 64);
    int*   offs   = (int*)(ws + 128);
    int*   ptok   = (int*)(ws + 256);
    float* pw     = (float*)(ws + 256 + (size_t)NE * T_TOK * 4);
    size_t cur = 256 + (size_t)NE * T_TOK * 8;
    cur = (cur + 511) & ~(size_t)511;

    unsigned short* xb = (unsigned short*)(ws + cur);
    cur += (size_t)T_TOK * DM * 2;

    const size_t wfull_bytes = (size_t)NE * DFF * DM * 2;
    const size_t hrow_total  = 2 * (size_t)T_TOK;

    int FFC = 0, wfull = 0;
    unsigned short *w1b = nullptr, *w2b = nullptr, *H = nullptr;
    for (int f = DFF; f >= 512; f >>= 1) {
        size_t need = cur + 2 * wfull_bytes + hrow_total * (size_t)f * 2;
        if (need <= ws_size) { FFC = f; wfull = 1; break; }
    }
    if (wfull) {
        w1b = (unsigned short*)(ws + cur); cur += wfull_bytes;
        w2b = (unsigned short*)(ws + cur); cur += wfull_bytes;
        H   = (unsigned short*)(ws + cur);
    } else {
        for (int f = 1024; f >= 512; f >>= 1) {
            size_t wc = (size_t)NE * f * DM * 2;
            size_t need = cur + 2 * wc + hrow_total * (size_t)f * 2;
            if (need <= ws_size) { FFC = f; break; }
        }
        if (FFC == 0) return;
        size_t wc = (size_t)NE * FFC * DM * 2;
        w1b = (unsigned short*)(ws + cur); cur += wc;
        w2b = (unsigned short*)(ws + cur); cur += wc;
        H   = (unsigned short*)(ws + cur);
    }

    hipMemsetAsync(ws, 0, 256, stream);
    hipMemsetAsync(d_out, 0, (size_t)out_size * 4, stream);

    router_kernel<<<T_TOK / 4, 256, 0, stream>>>(x, gw, counts, imp, ptok, pw);
    finalize_kernel<<<1, 64, 0, stream>>>(counts, imp, offs, out + (size_t)out_size - 1);

    {
        long long n = (long long)T_TOK * DM;
        conv_flat<<<(unsigned)(n / 1024), 256, 0, stream>>>(x, xb, n);
    }
    if (wfull) {
        long long n = (long long)NE * DFF * DM;
        conv_flat<<<(unsigned)(n / 1024), 256, 0, stream>>>(w1, w1b, n);
        conv_flat<<<(unsigned)(n / 1024), 256, 0, stream>>>(w2, w2b, n);
    }

    const int NCH = DFF / FFC;
    for (int c = 0; c < NCH; ++c) {
        if (!wfull) {
            dim3 gc1((unsigned)((long long)FFC * DM / 1024), NE);
            conv_rows<<<gc1, 256, 0, stream>>>(w1, w1b,
                (long long)c * FFC * DM, (long long)DFF * DM, FFC * DM);
            dim3 gc2((unsigned)((FFC + 1023) / 1024), NE * DM);
            conv_rows<<<gc2, 256, 0, stream>>>(w2, w2b,
                (long long)c * FFC, (long long)DFF, FFC);
        }
        dim3 g1(T_TOK / 128, FFC / 128, NE);
        gemm_bt<0><<<g1, 256, 0, stream>>>(xb, w1b, b1, counts, offs, ptok, pw, H, out, FFC, c, wfull);
        dim3 g2(T_TOK / 128, DM / 128, NE);
        gemm_bt<1><<<g2, 256, 0, stream>>>(H, w2b, b2, counts, offs, ptok, pw, H, out, FFC, c, wfull);
    }
}

// Round 7
// 2043.940 us; speedup vs baseline: 1.1367x; 1.0613x over previous
//
#include <hip/hip_runtime.h>
#include <cstdint>
#include <math.h>

#define T_TOK 8192
#define DM 1024
#define DFF 4096
#define NE 8

typedef __attribute__((ext_vector_type(8))) short short8;
typedef __attribute__((ext_vector_type(4))) float f32x4;

#define GLDS16(g, l) __builtin_amdgcn_global_load_lds( \
    (const __attribute__((address_space(1))) void*)(g), \
    (__attribute__((address_space(3))) void*)(l), 16, 0, 0)

#define FENCE asm volatile("" ::: "memory")

static __device__ __forceinline__ unsigned short f2bf(float f) {
    union { float f; unsigned int u; } v; v.f = f;
    unsigned int r = (v.u + 0x7FFFu + ((v.u >> 16) & 1u)) >> 16;
    return (unsigned short)r;
}

// ---------------- fp32 -> bf16 converters ----------------
__global__ __launch_bounds__(256) void conv_flat(const float* __restrict__ src,
                                                 unsigned short* __restrict__ dst,
                                                 long long n)
{
    long long i = ((long long)blockIdx.x * 256 + threadIdx.x) * 4;
    if (i >= n) return;
    const float4 v = *(const float4*)(src + i);
    uint2 u;
    u.x = (unsigned)f2bf(v.x) | ((unsigned)f2bf(v.y) << 16);
    u.y = (unsigned)f2bf(v.z) | ((unsigned)f2bf(v.w) << 16);
    *(uint2*)(dst + i) = u;
}

__global__ __launch_bounds__(256) void conv_rows(const float* __restrict__ src,
                                                 unsigned short* __restrict__ dst,
                                                 long long src_off, long long src_stride,
                                                 int ncols)
{
    long long row = blockIdx.y;
    int c = (blockIdx.x * 256 + threadIdx.x) * 4;
    if (c >= ncols) return;
    const float4 v = *(const float4*)(src + src_off + row * src_stride + c);
    uint2 u;
    u.x = (unsigned)f2bf(v.x) | ((unsigned)f2bf(v.y) << 16);
    u.y = (unsigned)f2bf(v.z) | ((unsigned)f2bf(v.w) << 16);
    *(uint2*)(dst + row * (long long)ncols + c) = u;
}

// ---------------- Router ----------------
__global__ __launch_bounds__(256) void router_kernel(
    const float* __restrict__ x, const float* __restrict__ gw,
    int* __restrict__ counts, float* __restrict__ imp,
    int* __restrict__ ptok, float* __restrict__ pw)
{
    __shared__ float4 sgw[NE * 256];
    __shared__ float simp[NE];
    const int tid = threadIdx.x;
    #pragma unroll
    for (int j = 0; j < 8; ++j) sgw[tid + j * 256] = ((const float4*)gw)[tid + j * 256];
    if (tid < NE) simp[tid] = 0.f;
    __syncthreads();

    const int wid = tid >> 6, lane = tid & 63;
    const int t = blockIdx.x * 4 + wid;
    float acc[NE];
    #pragma unroll
    for (int e = 0; e < NE; ++e) acc[e] = 0.f;
    const float4* xr = (const float4*)(x + (size_t)t * DM);
    #pragma unroll
    for (int j = 0; j < 4; ++j) {
        int idx = lane + j * 64;
        float4 xv = xr[idx];
        #pragma unroll
        for (int e = 0; e < NE; ++e) {
            float4 g = sgw[e * 256 + idx];
            acc[e] += xv.x * g.x + xv.y * g.y + xv.z * g.z + xv.w * g.w;
        }
    }
    #pragma unroll
    for (int off = 32; off; off >>= 1) {
        #pragma unroll
        for (int e = 0; e < NE; ++e) acc[e] += __shfl_xor(acc[e], off);
    }
    if (lane == 0) {
        float m = acc[0];
        #pragma unroll
        for (int e = 1; e < NE; ++e) m = fmaxf(m, acc[e]);
        float p[NE], s = 0.f;
        #pragma unroll
        for (int e = 0; e < NE; ++e) { p[e] = expf(acc[e] - m); s += p[e]; }
        float inv = 1.f / s;
        #pragma unroll
        for (int e = 0; e < NE; ++e) { p[e] *= inv; atomicAdd(&simp[e], p[e]); }
        int i0 = 0;
        #pragma unroll
        for (int e = 1; e < NE; ++e) if (p[e] > p[i0]) i0 = e;
        int i1 = (i0 == 0) ? 1 : 0;
        #pragma unroll
        for (int e = 0; e < NE; ++e) if (e != i0 && p[e] > p[i1]) i1 = e;
        float v0 = p[i0], v1 = p[i1], wsum = v0 + v1;
        int s0 = atomicAdd(&counts[i0], 1);
        ptok[i0 * T_TOK + s0] = t; pw[i0 * T_TOK + s0] = v0 / wsum;
        int s1 = atomicAdd(&counts[i1], 1);
        ptok[i1 * T_TOK + s1] = t; pw[i1 * T_TOK + s1] = v1 / wsum;
    }
    __syncthreads();
    if (tid < NE) atomicAdd(&imp[tid], simp[tid]);
}

__global__ void finalize_kernel(const int* __restrict__ counts,
                                const float* __restrict__ imp,
                                int* __restrict__ offs, float* __restrict__ aux_out)
{
    if (threadIdx.x == 0 && blockIdx.x == 0) {
        int o = 0; float aux = 0.f;
        for (int e = 0; e < NE; ++e) {
            offs[e] = o; o += counts[e];
            aux += (imp[e] / (float)T_TOK) * ((float)counts[e] / (float)(T_TOK * 2));
        }
        offs[NE] = o;
        *aux_out = (float)NE * aux;
    }
}

// ---------------- Grouped GEMM (B^T), 256x256, BK=64, 8 waves, 8-phase schedule ----------------
// LDS: 8 regions of 16KB: [buf(2)][kslice(2)][256 rows][32 K-cols] for A and B.
// Stage ring (distance ~2 tiles): ph0:B-K1(kt+1) ph1:A-K0(kt+2) ph2:B-K0(kt+2) ph3:A-K1(kt+2).
// vmcnt(6) once per tile before ph3's trailing barrier (per-wave wait + barrier = global).
// EPI==0: H[pair, f] = gelu(gather(xb) @ w1b[e]^T + b1)   (K = DM,  N = FFC chunk)
// EPI==1: out[tok,d] += w_pair * (H @ w2b[e]^T + b2)      (K = FFC, N = DM)
template<int EPI>
__global__ __launch_bounds__(512, 2) void gemm_bt(
    const unsigned short* __restrict__ A,
    const unsigned short* __restrict__ W,
    const float* __restrict__ bias,
    const int* __restrict__ counts, const int* __restrict__ offs,
    const int* __restrict__ ptok, const float* __restrict__ pw,
    unsigned short* __restrict__ Hout, float* __restrict__ out,
    int FFC, int cch, int wfull)
{
    const int e = blockIdx.z;
    const int n_e = counts[e];
    const int m0 = blockIdx.x * 256;
    if (m0 >= n_e) return;
    const int nt = blockIdx.y;
    const int KD = (EPI == 0) ? DM : FFC;
    const int NT = KD >> 6;
    const int hbase = offs[e];

    __shared__ unsigned short lA[2 * 2 * 256 * 32];  // 64 KB
    __shared__ unsigned short lB[2 * 2 * 256 * 32];  // 64 KB

    const int tid = threadIdx.x, lane = tid & 63, wid = tid >> 6;
    const int wr = wid >> 2, wc = wid & 3;           // 2M x 4N waves, wave tile 128x64
    const int lo = lane & 15, hi = lane >> 4;

    int wrow0; long long wstride, wcol0;
    if (EPI == 0) {
        wrow0 = e * (wfull ? DFF : FFC) + (wfull ? cch * FFC : 0) + nt * 256;
        wstride = DM; wcol0 = 0;
    } else {
        wrow0 = e * DM + nt * 256;
        wstride = (wfull ? DFF : FFC); wcol0 = (wfull ? (long long)cch * FFC : 0);
    }

    // staging source addresses: thread li=tid+j*512 -> (row r=li>>2, 16B slot s=li&3)
    // source column pre-swizzled (inverse of read swizzle) so linear LDS dest works
    const unsigned short* aaddr[2];
    const unsigned short* baddr[2];
    #pragma unroll
    for (int j = 0; j < 2; ++j) {
        int li = tid + j * 512;
        int r = li >> 2, s = li & 3;
        int sw = (s ^ ((r + (r >> 2)) & 3)) * 8;
        long long arow;
        int m = m0 + r;
        if (EPI == 0) {
            int tok = ptok[e * T_TOK + (m < n_e ? m : 0)];
            arow = (long long)tok * DM;
        } else {
            arow = (long long)(hbase + (m < n_e ? m : 0)) * FFC;
        }
        aaddr[j] = A + arow + sw;
        baddr[j] = W + (long long)(wrow0 + r) * wstride + wcol0 + sw;
    }

    // precomputed swizzled ds_read offsets (shorts, within a 16KB region)
    int offA[8], offB[4];
    #pragma unroll
    for (int mi = 0; mi < 8; ++mi) {
        int row = wr * 128 + mi * 16 + lo;
        offA[mi] = row * 32 + ((hi ^ ((row + (row >> 2)) & 3)) * 8);
    }
    #pragma unroll
    for (int nj = 0; nj < 4; ++nj) {
        int row = wc * 64 + nj * 16 + lo;
        offB[nj] = row * 32 + ((hi ^ ((row + (row >> 2)) & 3)) * 8);
    }

    f32x4 acc[8][4];
    #pragma unroll
    for (int i = 0; i < 8; ++i)
        #pragma unroll
        for (int j = 0; j < 4; ++j) acc[i][j] = (f32x4)0.f;

// stage one 16KB region (2 glds/thread). Region slot = [(tile&1)*2 + k] * 8192 shorts.
#define STG(LDSA, ADDR, tile, k) do { \
        const int _b = (((tile) & 1) * 2 + (k)) * 8192; \
        const long long _ko = (long long)(tile) * 64 + (k) * 32; \
        GLDS16((ADDR)[0] + _ko, &LDSA[_b + tid * 8]); \
        GLDS16((ADDR)[1] + _ko, &LDSA[_b + (tid + 512) * 8]); \
    } while (0)

#define MFMA_CL(g) do { \
        __builtin_amdgcn_s_setprio(1); \
        _Pragma("unroll") \
        for (int mi = 0; mi < 8; ++mi) { \
            acc[mi][2 * (g)]     = __builtin_amdgcn_mfma_f32_16x16x32_bf16(af[mi], bf0, acc[mi][2 * (g)], 0, 0, 0); \
            acc[mi][2 * (g) + 1] = __builtin_amdgcn_mfma_f32_16x16x32_bf16(af[mi], bf1, acc[mi][2 * (g) + 1], 0, 0, 0); \
        } \
        __builtin_amdgcn_s_setprio(0); \
    } while (0)

    // ---- prologue: tile0 all 4 regions + tile1 first 3, then vmcnt(6)+barrier ----
    STG(lA, aaddr, 0, 0); STG(lB, baddr, 0, 0);
    STG(lA, aaddr, 0, 1); STG(lB, baddr, 0, 1);
    STG(lA, aaddr, 1, 0); STG(lB, baddr, 1, 0);
    STG(lA, aaddr, 1, 1);
    asm volatile("s_waitcnt vmcnt(6)" ::: "memory");
    __builtin_amdgcn_s_barrier();
    FENCE;

    short8 af[8];

    for (int kt = 0; kt < NT; ++kt) {
        const int bA0 = ((kt & 1) * 2 + 0) * 8192;
        const int bA1 = ((kt & 1) * 2 + 1) * 8192;

        // ---- phase 0: k-slice 0, nj-group 0; stage B-K1(kt+1) ----
        {
            #pragma unroll
            for (int mi = 0; mi < 8; ++mi) af[mi] = *(const short8*)(&lA[bA0 + offA[mi]]);
            short8 bf0 = *(const short8*)(&lB[bA0 + offB[0]]);
            short8 bf1 = *(const short8*)(&lB[bA0 + offB[1]]);
            if (kt + 1 < NT) STG(lB, baddr, kt + 1, 1);
            FENCE; __builtin_amdgcn_s_barrier();
            asm volatile("s_waitcnt lgkmcnt(0)" ::: "memory");
            MFMA_CL(0);
            FENCE; __builtin_amdgcn_s_barrier(); FENCE;
        }
        // ---- phase 1: k-slice 0, nj-group 1; stage A-K0(kt+2) ----
        {
            short8 bf0 = *(const short8*)(&lB[bA0 + offB[2]]);
            short8 bf1 = *(const short8*)(&lB[bA0 + offB[3]]);
            if (kt + 2 < NT) STG(lA, aaddr, kt + 2, 0);
            FENCE; __builtin_amdgcn_s_barrier();
            asm volatile("s_waitcnt lgkmcnt(0)" ::: "memory");
            MFMA_CL(1);
            FENCE; __builtin_amdgcn_s_barrier(); FENCE;
        }
        // ---- phase 2: k-slice 1, nj-group 0; stage B-K0(kt+2) ----
        {
            #pragma unroll
            for (int mi = 0; mi < 8; ++mi) af[mi] = *(const short8*)(&lA[bA1 + offA[mi]]);
            short8 bf0 = *(const short8*)(&lB[bA1 + offB[0]]);
            short8 bf1 = *(const short8*)(&lB[bA1 + offB[1]]);
            if (kt + 2 < NT) STG(lB, baddr, kt + 2, 0);
            FENCE; __builtin_amdgcn_s_barrier();
            asm volatile("s_waitcnt lgkmcnt(0)" ::: "memory");
            MFMA_CL(0);
            FENCE; __builtin_amdgcn_s_barrier(); FENCE;
        }
        // ---- phase 3: k-slice 1, nj-group 1; stage A-K1(kt+2); vmcnt then barrier ----
        {
            short8 bf0 = *(const short8*)(&lB[bA1 + offB[2]]);
            short8 bf1 = *(const short8*)(&lB[bA1 + offB[3]]);
            if (kt + 2 < NT) STG(lA, aaddr, kt + 2, 1);
            FENCE; __builtin_amdgcn_s_barrier();
            asm volatile("s_waitcnt lgkmcnt(0)" ::: "memory");
            MFMA_CL(1);
            if (kt + 2 < NT) { asm volatile("s_waitcnt vmcnt(6)" ::: "memory"); }
            else             { asm volatile("s_waitcnt vmcnt(0)" ::: "memory"); }
            FENCE; __builtin_amdgcn_s_barrier(); FENCE;
        }
    }

    // ---- epilogue: wave writes its 128x64 sub-tile ----
    const int rbase = hi * 4;
    if (EPI == 0) {
        #pragma unroll
        for (int mi = 0; mi < 8; ++mi) {
            #pragma unroll
            for (int r = 0; r < 4; ++r) {
                int m = m0 + wr * 128 + mi * 16 + rbase + r;
                if (m >= n_e) continue;
                long long hrow = (long long)(hbase + m) * FFC;
                #pragma unroll
                for (int nj = 0; nj < 4; ++nj) {
                    int f = nt * 256 + wc * 64 + nj * 16 + lo;
                    float v = acc[mi][nj][r] + bias[e * DFF + cch * FFC + f];
                    float g = 0.5f * v * (1.f + erff(v * 0.70710678118654752f));
                    Hout[hrow + f] = f2bf(g);
                }
            }
        }
    } else {
        #pragma unroll
        for (int mi = 0; mi < 8; ++mi) {
            #pragma unroll
            for (int r = 0; r < 4; ++r) {
                int m = m0 + wr * 128 + mi * 16 + rbase + r;
                if (m >= n_e) continue;
                int pidx = e * T_TOK + m;
                int tok = ptok[pidx];
                float wgt = pw[pidx];
                float* orow = out + (long long)tok * DM;
                #pragma unroll
                for (int nj = 0; nj < 4; ++nj) {
                    int d = nt * 256 + wc * 64 + nj * 16 + lo;
                    float v = acc[mi][nj][r];
                    if (cch == 0) v += bias[e * DM + d];
                    atomicAdd(&orow[d], wgt * v);
                }
            }
        }
    }
}

extern "C" void kernel_launch(void* const* d_in, const int* in_sizes, int n_in,
                              void* d_out, int out_size, void* d_ws, size_t ws_size,
                              hipStream_t stream)
{
    const float* x  = (const float*)d_in[0];
    const float* gw = (const float*)d_in[1];
    const float* w1 = (const float*)d_in[2];
    const float* b1 = (const float*)d_in[3];
    const float* w2 = (const float*)d_in[4];
    const float* b2 = (const float*)d_in[5];
    float* out = (float*)d_out;

    char* ws = (char*)d_ws;
    int*   counts = (int*)ws;
    float* imp    = (float*)(ws + 64);
    int*   offs   = (int*)(ws + 128);
    int*   ptok   = (int*)(ws + 256);
    float* pw     = (float*)(ws + 256 + (size_t)NE * T_TOK * 4);
    size_t cur = 256 + (size_t)NE * T_TOK * 8;
    cur = (cur + 511) & ~(size_t)511;

    unsigned short* xb = (unsigned short*)(ws + cur);
    cur += (size_t)T_TOK * DM * 2;

    const size_t wfull_bytes = (size_t)NE * DFF * DM * 2;
    const size_t hrow_total  = 2 * (size_t)T_TOK;

    int FFC = 0, wfull = 0;
    unsigned short *w1b = nullptr, *w2b = nullptr, *H = nullptr;
    for (int f = DFF; f >= 512; f >>= 1) {
        size_t need = cur + 2 * wfull_bytes + hrow_total * (size_t)f * 2;
        if (need <= ws_size) { FFC = f; wfull = 1; break; }
    }
    if (wfull) {
        w1b = (unsigned short*)(ws + cur); cur += wfull_bytes;
        w2b = (unsigned short*)(ws + cur); cur += wfull_bytes;
        H   = (unsigned short*)(ws + cur);
    } else {
        for (int f = 1024; f >= 256; f >>= 1) {
            size_t wc = (size_t)NE * f * DM * 2;
            size_t need = cur + 2 * wc + hrow_total * (size_t)f * 2;
            if (need <= ws_size) { FFC = f; break; }
        }
        if (FFC == 0) return;
        size_t wc = (size_t)NE * FFC * DM * 2;
        w1b = (unsigned short*)(ws + cur); cur += wc;
        w2b = (unsigned short*)(ws + cur); cur += wc;
        H   = (unsigned short*)(ws + cur);
    }

    hipMemsetAsync(ws, 0, 256, stream);
    hipMemsetAsync(d_out, 0, (size_t)out_size * 4, stream);

    router_kernel<<<T_TOK / 4, 256, 0, stream>>>(x, gw, counts, imp, ptok, pw);
    finalize_kernel<<<1, 64, 0, stream>>>(counts, imp, offs, out + (size_t)out_size - 1);

    {
        long long n = (long long)T_TOK * DM;
        conv_flat<<<(unsigned)(n / 1024), 256, 0, stream>>>(x, xb, n);
    }
    if (wfull) {
        long long n = (long long)NE * DFF * DM;
        conv_flat<<<(unsigned)(n / 1024), 256, 0, stream>>>(w1, w1b, n);
        conv_flat<<<(unsigned)(n / 1024), 256, 0, stream>>>(w2, w2b, n);
    }

    const int NCH = DFF / FFC;
    for (int c = 0; c < NCH; ++c) {
        if (!wfull) {
            dim3 gc1((unsigned)((long long)FFC * DM / 1024), NE);
            conv_rows<<<gc1, 256, 0, stream>>>(w1, w1b,
                (long long)c * FFC * DM, (long long)DFF * DM, FFC * DM);
            dim3 gc2((unsigned)((FFC + 1023) / 1024), NE * DM);
            conv_rows<<<gc2, 256, 0, stream>>>(w2, w2b,
                (long long)c * FFC, (long long)DFF, FFC);
        }
        dim3 g1(T_TOK / 256, FFC / 256, NE);
        gemm_bt<0><<<g1, 512, 0, stream>>>(xb, w1b, b1, counts, offs, ptok, pw, H, out, FFC, c, wfull);
        dim3 g2(T_TOK / 256, DM / 256, NE);
        gemm_bt<1><<<g2, 512, 0, stream>>>(H, w2b, b2, counts, offs, ptok, pw, H, out, FFC, c, wfull);
    }
}

// Round 8
// 1015.509 us; speedup vs baseline: 2.2879x; 2.0127x over previous
//
#include <hip/hip_runtime.h>
#include <cstdint>
#include <math.h>

#define T_TOK 8192
#define DM 1024
#define DFF 4096
#define NE 8
#define WLMAX 136   // max m-tiles: 16384/128 + 8

typedef __attribute__((ext_vector_type(8))) short short8;
typedef __attribute__((ext_vector_type(4))) float f32x4;

#define GLDS16(g, l) __builtin_amdgcn_global_load_lds( \
    (const __attribute__((address_space(1))) void*)(g), \
    (__attribute__((address_space(3))) void*)(l), 16, 0, 0)

static __device__ __forceinline__ unsigned short f2bf(float f) {
    union { float f; unsigned int u; } v; v.f = f;
    unsigned int r = (v.u + 0x7FFFu + ((v.u >> 16) & 1u)) >> 16;
    return (unsigned short)r;
}

// ---------------- fp32 -> bf16 converters ----------------
__global__ __launch_bounds__(256) void conv_flat(const float* __restrict__ src,
                                                 unsigned short* __restrict__ dst,
                                                 long long n)
{
    long long i = ((long long)blockIdx.x * 256 + threadIdx.x) * 4;
    if (i >= n) return;
    const float4 v = *(const float4*)(src + i);
    uint2 u;
    u.x = (unsigned)f2bf(v.x) | ((unsigned)f2bf(v.y) << 16);
    u.y = (unsigned)f2bf(v.z) | ((unsigned)f2bf(v.w) << 16);
    *(uint2*)(dst + i) = u;
}

__global__ __launch_bounds__(256) void conv_rows(const float* __restrict__ src,
                                                 unsigned short* __restrict__ dst,
                                                 long long src_off, long long src_stride,
                                                 int ncols)
{
    long long row = blockIdx.y;
    int c = (blockIdx.x * 256 + threadIdx.x) * 4;
    if (c >= ncols) return;
    const float4 v = *(const float4*)(src + src_off + row * src_stride + c);
    uint2 u;
    u.x = (unsigned)f2bf(v.x) | ((unsigned)f2bf(v.y) << 16);
    u.y = (unsigned)f2bf(v.z) | ((unsigned)f2bf(v.w) << 16);
    *(uint2*)(dst + row * (long long)ncols + c) = u;
}

// ---------------- Router ----------------
__global__ __launch_bounds__(256) void router_kernel(
    const float* __restrict__ x, const float* __restrict__ gw,
    int* __restrict__ counts, float* __restrict__ imp,
    int* __restrict__ ptok, float* __restrict__ pw)
{
    __shared__ float4 sgw[NE * 256];
    __shared__ float simp[NE];
    const int tid = threadIdx.x;
    #pragma unroll
    for (int j = 0; j < 8; ++j) sgw[tid + j * 256] = ((const float4*)gw)[tid + j * 256];
    if (tid < NE) simp[tid] = 0.f;
    __syncthreads();

    const int wid = tid >> 6, lane = tid & 63;
    const int t = blockIdx.x * 4 + wid;
    float acc[NE];
    #pragma unroll
    for (int e = 0; e < NE; ++e) acc[e] = 0.f;
    const float4* xr = (const float4*)(x + (size_t)t * DM);
    #pragma unroll
    for (int j = 0; j < 4; ++j) {
        int idx = lane + j * 64;
        float4 xv = xr[idx];
        #pragma unroll
        for (int e = 0; e < NE; ++e) {
            float4 g = sgw[e * 256 + idx];
            acc[e] += xv.x * g.x + xv.y * g.y + xv.z * g.z + xv.w * g.w;
        }
    }
    #pragma unroll
    for (int off = 32; off; off >>= 1) {
        #pragma unroll
        for (int e = 0; e < NE; ++e) acc[e] += __shfl_xor(acc[e], off);
    }
    if (lane == 0) {
        float m = acc[0];
        #pragma unroll
        for (int e = 1; e < NE; ++e) m = fmaxf(m, acc[e]);
        float p[NE], s = 0.f;
        #pragma unroll
        for (int e = 0; e < NE; ++e) { p[e] = expf(acc[e] - m); s += p[e]; }
        float inv = 1.f / s;
        #pragma unroll
        for (int e = 0; e < NE; ++e) { p[e] *= inv; atomicAdd(&simp[e], p[e]); }
        int i0 = 0;
        #pragma unroll
        for (int e = 1; e < NE; ++e) if (p[e] > p[i0]) i0 = e;
        int i1 = (i0 == 0) ? 1 : 0;
        #pragma unroll
        for (int e = 0; e < NE; ++e) if (e != i0 && p[e] > p[i1]) i1 = e;
        float v0 = p[i0], v1 = p[i1], wsum = v0 + v1;
        int s0 = atomicAdd(&counts[i0], 1);
        ptok[i0 * T_TOK + s0] = t; pw[i0 * T_TOK + s0] = v0 / wsum;
        int s1 = atomicAdd(&counts[i1], 1);
        ptok[i1 * T_TOK + s1] = t; pw[i1 * T_TOK + s1] = v1 / wsum;
    }
    __syncthreads();
    if (tid < NE) atomicAdd(&imp[tid], simp[tid]);
}

// ---------------- Finalize: offsets + aux loss + dense work-list ----------------
__global__ void finalize_kernel(const int* __restrict__ counts,
                                const float* __restrict__ imp,
                                int* __restrict__ offs, int* __restrict__ wl,
                                float* __restrict__ aux_out)
{
    if (threadIdx.x == 0 && blockIdx.x == 0) {
        int o = 0; float aux = 0.f;
        for (int e = 0; e < NE; ++e) {
            offs[e] = o; o += counts[e];
            aux += (imp[e] / (float)T_TOK) * ((float)counts[e] / (float)(T_TOK * 2));
        }
        offs[NE] = o;
        int it = 0;
        for (int e = 0; e < NE; ++e) {
            int mts = (counts[e] + 127) >> 7;
            for (int mt = 0; mt < mts; ++mt) wl[it++] = (e << 16) | mt;
        }
        for (; it < WLMAX; ++it) wl[it] = -1;
        *aux_out = (float)NE * aux;
    }
}

// ---------------- Pre-gather: xg[offs[e]+slot][:] = bf16(x[ptok[e][slot]][:]) ----------------
__global__ __launch_bounds__(256) void pregather_kernel(
    const float* __restrict__ x, const int* __restrict__ counts,
    const int* __restrict__ offs, const int* __restrict__ ptok,
    unsigned short* __restrict__ xg)
{
    const int e = blockIdx.y;
    const int slot = blockIdx.x * 4 + (threadIdx.x >> 6);
    if (slot >= counts[e]) return;
    const int tok = ptok[e * T_TOK + slot];
    const int lane = threadIdx.x & 63;
    const float4* src = (const float4*)(x + (size_t)tok * DM);
    uint2* dst = (uint2*)(xg + (size_t)(offs[e] + slot) * DM);
    #pragma unroll
    for (int j = 0; j < 4; ++j) {
        float4 v = src[lane + j * 64];
        uint2 u;
        u.x = (unsigned)f2bf(v.x) | ((unsigned)f2bf(v.y) << 16);
        u.y = (unsigned)f2bf(v.z) | ((unsigned)f2bf(v.w) << 16);
        dst[lane + j * 64] = u;
    }
}

// ---------------- Grouped GEMM (B^T), 128x128, BK=64, m97 core + dense work-list ----------------
// Work item (from wl, XCD-chunked): e = item>>16, mt = item&0xffff; rows = [offs[e]+mt*128 ...).
// A is CONTIGUOUS (xg for EPI0, H for EPI1) — no gather in the hot loop.
// EPI==0: H[row, f] = gelu(xg @ w1b[e]^T + b1)   (K = DM,  N = FFC chunk)
// EPI==1: out[tok,d] += w_pair * (H @ w2b[e]^T + b2)   (K = FFC, N = DM)
template<int EPI>
__global__ __launch_bounds__(256) void gemm_bt(
    const unsigned short* __restrict__ A,
    const unsigned short* __restrict__ W,
    const float* __restrict__ bias,
    const int* __restrict__ counts, const int* __restrict__ offs,
    const int* __restrict__ ptok, const float* __restrict__ pw,
    const int* __restrict__ wl,
    unsigned short* __restrict__ Hout, float* __restrict__ out,
    int FFC, int cch, int wfull)
{
    // bijective XCD chunk remap (136 = 8*17): consecutive items share an XCD's L2
    const int bx = blockIdx.x;
    const int item = wl[(bx & 7) * 17 + (bx >> 3)];
    if (item < 0) return;
    const int e = item >> 16, mt = item & 0xffff;
    const int n_e = counts[e];
    int rows_here = n_e - mt * 128; if (rows_here > 128) rows_here = 128;
    const long long row_lo = (long long)offs[e] + (long long)mt * 128;
    const int nt = blockIdx.y;
    const int KD = (EPI == 0) ? DM : FFC;

    __shared__ unsigned short lA[128 * 64];   // 16 KB
    __shared__ unsigned short lB[128 * 64];   // 16 KB

    const int tid = threadIdx.x, lane = tid & 63, wid = tid >> 6;
    const int msub = (wid & 1) * 64, nsub = (wid >> 1) * 64;
    const int hi = lane >> 4, lo = lane & 15;

    int wrow0; long long wstride, wcol0;
    if (EPI == 0) {
        wrow0 = e * (wfull ? DFF : FFC) + (wfull ? cch * FFC : 0) + nt * 128;
        wstride = DM; wcol0 = 0;
    } else {
        wrow0 = e * DM + nt * 128;
        wstride = (wfull ? DFF : FFC); wcol0 = (wfull ? (long long)cch * FFC : 0);
    }

    // staging source addresses, column pre-swizzled (inverse of read swizzle);
    // linear glds dest + XOR'd ds_read = identity (rule #21; R3-verified, 0 conflicts)
    const unsigned short* aaddr[4];
    const unsigned short* baddr[4];
    #pragma unroll
    for (int j = 0; j < 4; ++j) {
        int li = tid + j * 256;
        int r = li >> 3;
        int scol = ((li & 7) ^ (r & 7)) * 8;
        int rc = (r < rows_here) ? r : (rows_here - 1);
        aaddr[j] = A + (row_lo + rc) * KD + scol;
        baddr[j] = W + (long long)(wrow0 + r) * wstride + wcol0 + scol;
    }

    f32x4 acc[4][4];
    #pragma unroll
    for (int i = 0; i < 4; ++i)
        #pragma unroll
        for (int j = 0; j < 4; ++j) acc[i][j] = (f32x4)0.f;

    const int NT = KD >> 6;
    for (int t = 0; t < NT; ++t) {
        const long long k0 = (long long)t * 64;
        #pragma unroll
        for (int j = 0; j < 4; ++j) {
            GLDS16(aaddr[j] + k0, &lA[(tid + j * 256) * 8]);
            GLDS16(baddr[j] + k0, &lB[(tid + j * 256) * 8]);
        }
        __syncthreads();
        #pragma unroll
        for (int kk = 0; kk < 2; ++kk) {
            const int soff = ((kk * 4 + hi) ^ (lo & 7)) * 8;
            short8 af[4], bf[4];
            #pragma unroll
            for (int i = 0; i < 4; ++i) {
                af[i] = *(const short8*)(&lA[(msub + i * 16 + lo) * 64 + soff]);
                bf[i] = *(const short8*)(&lB[(nsub + i * 16 + lo) * 64 + soff]);
            }
            #pragma unroll
            for (int mi = 0; mi < 4; ++mi)
                #pragma unroll
                for (int nj = 0; nj < 4; ++nj)
                    acc[mi][nj] = __builtin_amdgcn_mfma_f32_16x16x32_bf16(af[mi], bf[nj], acc[mi][nj], 0, 0, 0);
        }
        __syncthreads();
    }

    const int rbase = hi * 4, cidx = lo;
    if (EPI == 0) {
        #pragma unroll
        for (int mi = 0; mi < 4; ++mi) {
            #pragma unroll
            for (int r = 0; r < 4; ++r) {
                int mloc = msub + mi * 16 + rbase + r;
                if (mloc >= rows_here) continue;
                long long hrow = (row_lo + mloc) * FFC;
                #pragma unroll
                for (int nj = 0; nj < 4; ++nj) {
                    int f = nt * 128 + nsub + nj * 16 + cidx;
                    float v = acc[mi][nj][r] + bias[e * DFF + cch * FFC + f];
                    float g = 0.5f * v * (1.f + erff(v * 0.70710678118654752f));
                    Hout[hrow + f] = f2bf(g);
                }
            }
        }
    } else {
        #pragma unroll
        for (int mi = 0; mi < 4; ++mi) {
            #pragma unroll
            for (int r = 0; r < 4; ++r) {
                int mloc = msub + mi * 16 + rbase + r;
                if (mloc >= rows_here) continue;
                int pidx = e * T_TOK + mt * 128 + mloc;
                int tok = ptok[pidx];
                float wgt = pw[pidx];
                float* orow = out + (long long)tok * DM;
                #pragma unroll
                for (int nj = 0; nj < 4; ++nj) {
                    int d = nt * 128 + nsub + nj * 16 + cidx;
                    float v = acc[mi][nj][r];
                    if (cch == 0) v += bias[e * DM + d];
                    atomicAdd(&orow[d], wgt * v);
                }
            }
        }
    }
}

extern "C" void kernel_launch(void* const* d_in, const int* in_sizes, int n_in,
                              void* d_out, int out_size, void* d_ws, size_t ws_size,
                              hipStream_t stream)
{
    const float* x  = (const float*)d_in[0];
    const float* gw = (const float*)d_in[1];
    const float* w1 = (const float*)d_in[2];
    const float* b1 = (const float*)d_in[3];
    const float* w2 = (const float*)d_in[4];
    const float* b2 = (const float*)d_in[5];
    float* out = (float*)d_out;

    char* ws = (char*)d_ws;
    int*   counts = (int*)ws;                 // 0
    float* imp    = (float*)(ws + 64);        // 64
    int*   offs   = (int*)(ws + 128);         // 128 (9 ints)
    int*   wl     = (int*)(ws + 192);         // 192 (136 ints, ends 736)
    int*   ptok   = (int*)(ws + 1024);
    float* pw     = (float*)(ws + 1024 + (size_t)NE * T_TOK * 4);
    size_t cur = 1024 + (size_t)NE * T_TOK * 8;
    cur = (cur + 511) & ~(size_t)511;

    unsigned short* xg = (unsigned short*)(ws + cur);   // expert-sorted pairs, 33.5 MB
    cur += (size_t)2 * T_TOK * DM * 2;

    const size_t wfull_bytes = (size_t)NE * DFF * DM * 2;
    const size_t hrow_total  = 2 * (size_t)T_TOK;

    int FFC = 0, wfull = 0;
    unsigned short *w1b = nullptr, *w2b = nullptr, *H = nullptr;
    for (int f = DFF; f >= 512; f >>= 1) {
        size_t need = cur + 2 * wfull_bytes + hrow_total * (size_t)f * 2;
        if (need <= ws_size) { FFC = f; wfull = 1; break; }
    }
    if (wfull) {
        w1b = (unsigned short*)(ws + cur); cur += wfull_bytes;
        w2b = (unsigned short*)(ws + cur); cur += wfull_bytes;
        H   = (unsigned short*)(ws + cur);
    } else {
        for (int f = 1024; f >= 256; f >>= 1) {
            size_t wc = (size_t)NE * f * DM * 2;
            size_t need = cur + 2 * wc + hrow_total * (size_t)f * 2;
            if (need <= ws_size) { FFC = f; break; }
        }
        if (FFC == 0) return;
        size_t wc = (size_t)NE * FFC * DM * 2;
        w1b = (unsigned short*)(ws + cur); cur += wc;
        w2b = (unsigned short*)(ws + cur); cur += wc;
        H   = (unsigned short*)(ws + cur);
    }

    hipMemsetAsync(ws, 0, 256, stream);
    hipMemsetAsync(d_out, 0, (size_t)out_size * 4, stream);

    router_kernel<<<T_TOK / 4, 256, 0, stream>>>(x, gw, counts, imp, ptok, pw);
    finalize_kernel<<<1, 64, 0, stream>>>(counts, imp, offs, wl, out + (size_t)out_size - 1);
    {
        dim3 gp(T_TOK / 4, NE);
        pregather_kernel<<<gp, 256, 0, stream>>>(x, counts, offs, ptok, xg);
    }
    if (wfull) {
        long long n = (long long)NE * DFF * DM;
        conv_flat<<<(unsigned)(n / 1024), 256, 0, stream>>>(w1, w1b, n);
        conv_flat<<<(unsigned)(n / 1024), 256, 0, stream>>>(w2, w2b, n);
    }

    const int NCH = DFF / FFC;
    for (int c = 0; c < NCH; ++c) {
        if (!wfull) {
            dim3 gc1((unsigned)((long long)FFC * DM / 1024), NE);
            conv_rows<<<gc1, 256, 0, stream>>>(w1, w1b,
                (long long)c * FFC * DM, (long long)DFF * DM, FFC * DM);
            dim3 gc2((unsigned)((FFC + 1023) / 1024), NE * DM);
            conv_rows<<<gc2, 256, 0, stream>>>(w2, w2b,
                (long long)c * FFC, (long long)DFF, FFC);
        }
        dim3 g1(WLMAX, FFC / 128, 1);
        gemm_bt<0><<<g1, 256, 0, stream>>>(xg, w1b, b1, counts, offs, ptok, pw, wl, H, out, FFC, c, wfull);
        dim3 g2(WLMAX, DM / 128, 1);
        gemm_bt<1><<<g2, 256, 0, stream>>>(H, w2b, b2, counts, offs, ptok, pw, wl, H, out, FFC, c, wfull);
    }
}

// Round 9
// 812.668 us; speedup vs baseline: 2.8589x; 1.2496x over previous
//
#include <hip/hip_runtime.h>
#include <cstdint>
#include <math.h>

#define T_TOK 8192
#define DM 1024
#define DFF 4096
#define NE 8
#define WLMAX 136   // max 128-row m-tiles: 16384/128 + 8

typedef __attribute__((ext_vector_type(8))) short short8;
typedef __attribute__((ext_vector_type(4))) float f32x4;

#define GLDS16(g, l) __builtin_amdgcn_global_load_lds( \
    (const __attribute__((address_space(1))) void*)(g), \
    (__attribute__((address_space(3))) void*)(l), 16, 0, 0)

static __device__ __forceinline__ unsigned short f2bf(float f) {
    union { float f; unsigned int u; } v; v.f = f;
    unsigned int r = (v.u + 0x7FFFu + ((v.u >> 16) & 1u)) >> 16;
    return (unsigned short)r;
}

// gelu with Abramowitz-Stegun 7.1.26 erf (|err| < 1.5e-7, safe under bf16 rounding)
static __device__ __forceinline__ float gelu_f(float v) {
    float z = fabsf(v) * 0.70710678118654752f;
    float t = 1.f / (1.f + 0.3275911f * z);
    float p = t * (0.254829592f + t * (-0.284496736f + t * (1.421413741f +
              t * (-1.453152027f + t * 1.061405429f))));
    float erfz = 1.f - p * __expf(-z * z);
    float s = (v >= 0.f) ? erfz : -erfz;
    return 0.5f * v * (1.f + s);
}

// ---------------- fp32 -> bf16 converters ----------------
__global__ __launch_bounds__(256) void conv_flat(const float* __restrict__ src,
                                                 unsigned short* __restrict__ dst,
                                                 long long n)
{
    long long i = ((long long)blockIdx.x * 256 + threadIdx.x) * 4;
    if (i >= n) return;
    const float4 v = *(const float4*)(src + i);
    uint2 u;
    u.x = (unsigned)f2bf(v.x) | ((unsigned)f2bf(v.y) << 16);
    u.y = (unsigned)f2bf(v.z) | ((unsigned)f2bf(v.w) << 16);
    *(uint2*)(dst + i) = u;
}

__global__ __launch_bounds__(256) void conv_rows(const float* __restrict__ src,
                                                 unsigned short* __restrict__ dst,
                                                 long long src_off, long long src_stride,
                                                 int ncols)
{
    long long row = blockIdx.y;
    int c = (blockIdx.x * 256 + threadIdx.x) * 4;
    if (c >= ncols) return;
    const float4 v = *(const float4*)(src + src_off + row * src_stride + c);
    uint2 u;
    u.x = (unsigned)f2bf(v.x) | ((unsigned)f2bf(v.y) << 16);
    u.y = (unsigned)f2bf(v.z) | ((unsigned)f2bf(v.w) << 16);
    *(uint2*)(dst + row * (long long)ncols + c) = u;
}

// ---------------- Router ----------------
__global__ __launch_bounds__(256) void router_kernel(
    const float* __restrict__ x, const float* __restrict__ gw,
    int* __restrict__ counts, float* __restrict__ imp,
    int* __restrict__ ptok, float* __restrict__ pw)
{
    __shared__ float4 sgw[NE * 256];
    __shared__ float simp[NE];
    const int tid = threadIdx.x;
    #pragma unroll
    for (int j = 0; j < 8; ++j) sgw[tid + j * 256] = ((const float4*)gw)[tid + j * 256];
    if (tid < NE) simp[tid] = 0.f;
    __syncthreads();

    const int wid = tid >> 6, lane = tid & 63;
    const int t = blockIdx.x * 4 + wid;
    float acc[NE];
    #pragma unroll
    for (int e = 0; e < NE; ++e) acc[e] = 0.f;
    const float4* xr = (const float4*)(x + (size_t)t * DM);
    #pragma unroll
    for (int j = 0; j < 4; ++j) {
        int idx = lane + j * 64;
        float4 xv = xr[idx];
        #pragma unroll
        for (int e = 0; e < NE; ++e) {
            float4 g = sgw[e * 256 + idx];
            acc[e] += xv.x * g.x + xv.y * g.y + xv.z * g.z + xv.w * g.w;
        }
    }
    #pragma unroll
    for (int off = 32; off; off >>= 1) {
        #pragma unroll
        for (int e = 0; e < NE; ++e) acc[e] += __shfl_xor(acc[e], off);
    }
    if (lane == 0) {
        float m = acc[0];
        #pragma unroll
        for (int e = 1; e < NE; ++e) m = fmaxf(m, acc[e]);
        float p[NE], s = 0.f;
        #pragma unroll
        for (int e = 0; e < NE; ++e) { p[e] = expf(acc[e] - m); s += p[e]; }
        float inv = 1.f / s;
        #pragma unroll
        for (int e = 0; e < NE; ++e) { p[e] *= inv; atomicAdd(&simp[e], p[e]); }
        int i0 = 0;
        #pragma unroll
        for (int e = 1; e < NE; ++e) if (p[e] > p[i0]) i0 = e;
        int i1 = (i0 == 0) ? 1 : 0;
        #pragma unroll
        for (int e = 0; e < NE; ++e) if (e != i0 && p[e] > p[i1]) i1 = e;
        float v0 = p[i0], v1 = p[i1], wsum = v0 + v1;
        int s0 = atomicAdd(&counts[i0], 1);
        ptok[i0 * T_TOK + s0] = t; pw[i0 * T_TOK + s0] = v0 / wsum;
        int s1 = atomicAdd(&counts[i1], 1);
        ptok[i1 * T_TOK + s1] = t; pw[i1 * T_TOK + s1] = v1 / wsum;
    }
    __syncthreads();
    if (tid < NE) atomicAdd(&imp[tid], simp[tid]);
}

// ---------------- Finalize: offsets + aux loss + dense work-list ----------------
__global__ void finalize_kernel(const int* __restrict__ counts,
                                const float* __restrict__ imp,
                                int* __restrict__ offs, int* __restrict__ wl,
                                float* __restrict__ aux_out)
{
    if (threadIdx.x == 0 && blockIdx.x == 0) {
        int o = 0; float aux = 0.f;
        for (int e = 0; e < NE; ++e) {
            offs[e] = o; o += counts[e];
            aux += (imp[e] / (float)T_TOK) * ((float)counts[e] / (float)(T_TOK * 2));
        }
        offs[NE] = o;
        int it = 0;
        for (int e = 0; e < NE; ++e) {
            int mts = (counts[e] + 127) >> 7;
            for (int mt = 0; mt < mts; ++mt) wl[it++] = (e << 16) | mt;
        }
        for (; it < WLMAX; ++it) wl[it] = -1;
        *aux_out = (float)NE * aux;
    }
}

// ---------------- Pre-gather + tok->pair map ----------------
__global__ __launch_bounds__(256) void pregather_kernel(
    const float* __restrict__ x, const int* __restrict__ counts,
    const int* __restrict__ offs, const int* __restrict__ ptok,
    unsigned short* __restrict__ xg, int* __restrict__ tc, int* __restrict__ tokpair)
{
    const int e = blockIdx.y;
    const int slot = blockIdx.x * 4 + (threadIdx.x >> 6);
    if (slot >= counts[e]) return;
    const int tok = ptok[e * T_TOK + slot];
    const int lane = threadIdx.x & 63;
    const int p = offs[e] + slot;
    if (lane == 0) {
        int k = atomicAdd(&tc[tok], 1);   // order nondet; out = yv[a]+yv[b] commutative
        tokpair[tok * 2 + k] = p;
    }
    const float4* src = (const float4*)(x + (size_t)tok * DM);
    uint2* dst = (uint2*)(xg + (size_t)p * DM);
    #pragma unroll
    for (int j = 0; j < 4; ++j) {
        float4 v = src[lane + j * 64];
        uint2 u;
        u.x = (unsigned)f2bf(v.x) | ((unsigned)f2bf(v.y) << 16);
        u.y = (unsigned)f2bf(v.z) | ((unsigned)f2bf(v.w) << 16);
        dst[lane + j * 64] = u;
    }
}

// ---------------- Combine: out[t] = yv[p0] + yv[p1] ----------------
__global__ __launch_bounds__(256) void combine_kernel(
    const float* __restrict__ yv, const int* __restrict__ tokpair,
    float* __restrict__ out)
{
    const int t = blockIdx.x;
    const int c = threadIdx.x;
    const long long p0 = tokpair[t * 2], p1 = tokpair[t * 2 + 1];
    const float4 a = ((const float4*)(yv + p0 * DM))[c];
    const float4 b = ((const float4*)(yv + p1 * DM))[c];
    float4 o;
    o.x = a.x + b.x; o.y = a.y + b.y; o.z = a.z + b.z; o.w = a.w + b.w;
    ((float4*)(out + (long long)t * DM))[c] = o;
}

// ---------------- Grouped GEMM (B^T), 128x256 tile, BK=64, 4 waves, m97 core ----------------
// wave-tile 128x64; per wave/K-step: 12 ds_read_b128 + 64 MFMA. LDS 48 KB single-buffer.
// EPI==0: H[row, f] = gelu(xg @ w1b[e]^T + b1)       (K = DM,  N = FFC chunk)
// EPI==1: yv[row,d] (=/+=) wgt*(H @ w2b[e]^T + b2)   (K = FFC, N = DM), no atomics
template<int EPI>
__global__ __launch_bounds__(256, 2) void gemm_bt(
    const unsigned short* __restrict__ A,
    const unsigned short* __restrict__ W,
    const float* __restrict__ bias,
    const int* __restrict__ counts, const int* __restrict__ offs,
    const int* __restrict__ ptok, const float* __restrict__ pw,
    const int* __restrict__ wl,
    unsigned short* __restrict__ Hout, float* __restrict__ yv,
    int FFC, int cch, int wfull)
{
    const int bx = blockIdx.x;
    const int item = wl[(bx & 7) * 17 + (bx >> 3)];   // bijective XCD chunking (136=8*17)
    if (item < 0) return;
    const int e = item >> 16, mt = item & 0xffff;
    const int n_e = counts[e];
    int rows_here = n_e - mt * 128; if (rows_here > 128) rows_here = 128;
    const long long row_lo = (long long)offs[e] + (long long)mt * 128;
    const int nt = blockIdx.y;
    const int KD = (EPI == 0) ? DM : FFC;

    __shared__ unsigned short lA[128 * 64];   // 16 KB
    __shared__ unsigned short lB[256 * 64];   // 32 KB

    const int tid = threadIdx.x, lane = tid & 63, wid = tid >> 6;
    const int nsub = wid * 64;                // 4 waves across N=256
    const int hi = lane >> 4, lo = lane & 15;

    int wrow0; long long wstride, wcol0;
    if (EPI == 0) {
        wrow0 = e * (wfull ? DFF : FFC) + (wfull ? cch * FFC : 0) + nt * 256;
        wstride = DM; wcol0 = 0;
    } else {
        wrow0 = e * DM + nt * 256;
        wstride = (wfull ? DFF : FFC); wcol0 = (wfull ? (long long)cch * FFC : 0);
    }

    // staging sources, column pre-swizzled (inverse of read swizzle; rule #21, R3-verified)
    const unsigned short* aaddr[4];
    #pragma unroll
    for (int j = 0; j < 4; ++j) {
        int li = tid + j * 256;
        int r = li >> 3;
        int scol = ((li & 7) ^ (r & 7)) * 8;
        int rc = (r < rows_here) ? r : (rows_here - 1);
        aaddr[j] = A + (row_lo + rc) * KD + scol;
    }
    const unsigned short* baddr[8];
    #pragma unroll
    for (int j = 0; j < 8; ++j) {
        int li = tid + j * 256;
        int r = li >> 3;
        int scol = ((li & 7) ^ (r & 7)) * 8;
        baddr[j] = W + (long long)(wrow0 + r) * wstride + wcol0 + scol;
    }

    f32x4 acc[8][4];
    #pragma unroll
    for (int i = 0; i < 8; ++i)
        #pragma unroll
        for (int j = 0; j < 4; ++j) acc[i][j] = (f32x4)0.f;

    const int NT = KD >> 6;
    for (int t = 0; t < NT; ++t) {
        const long long k0 = (long long)t * 64;
        #pragma unroll
        for (int j = 0; j < 4; ++j) GLDS16(aaddr[j] + k0, &lA[(tid + j * 256) * 8]);
        #pragma unroll
        for (int j = 0; j < 8; ++j) GLDS16(baddr[j] + k0, &lB[(tid + j * 256) * 8]);
        __syncthreads();
        #pragma unroll
        for (int kk = 0; kk < 2; ++kk) {
            short8 af[8], bf[4];
            #pragma unroll
            for (int mi = 0; mi < 8; ++mi) {
                int row = mi * 16 + lo;
                af[mi] = *(const short8*)(&lA[row * 64 + (((kk * 4 + hi) ^ (row & 7)) * 8)]);
            }
            #pragma unroll
            for (int nj = 0; nj < 4; ++nj) {
                int row = nsub + nj * 16 + lo;
                bf[nj] = *(const short8*)(&lB[row * 64 + (((kk * 4 + hi) ^ (row & 7)) * 8)]);
            }
            #pragma unroll
            for (int mi = 0; mi < 8; ++mi)
                #pragma unroll
                for (int nj = 0; nj < 4; ++nj)
                    acc[mi][nj] = __builtin_amdgcn_mfma_f32_16x16x32_bf16(af[mi], bf[nj], acc[mi][nj], 0, 0, 0);
        }
        __syncthreads();
    }

    const int rbase = hi * 4;
    if (EPI == 0) {
        #pragma unroll
        for (int mi = 0; mi < 8; ++mi) {
            #pragma unroll
            for (int r = 0; r < 4; ++r) {
                int m = mi * 16 + rbase + r;
                if (m >= rows_here) continue;
                long long hrow = (row_lo + m) * FFC;
                #pragma unroll
                for (int nj = 0; nj < 4; ++nj) {
                    int f = nt * 256 + nsub + nj * 16 + lo;
                    float v = acc[mi][nj][r] + bias[e * DFF + cch * FFC + f];
                    Hout[hrow + f] = f2bf(gelu_f(v));
                }
            }
        }
    } else {
        #pragma unroll
        for (int mi = 0; mi < 8; ++mi) {
            #pragma unroll
            for (int r = 0; r < 4; ++r) {
                int m = mi * 16 + rbase + r;
                if (m >= rows_here) continue;
                int pidx = e * T_TOK + mt * 128 + m;
                float wgt = pw[pidx];
                float* yrow = yv + (row_lo + m) * DM;
                #pragma unroll
                for (int nj = 0; nj < 4; ++nj) {
                    int d = nt * 256 + nsub + nj * 16 + lo;
                    float v = acc[mi][nj][r];
                    if (cch == 0) yrow[d] = wgt * (v + bias[e * DM + d]);
                    else          yrow[d] += wgt * v;
                }
            }
        }
    }
}

extern "C" void kernel_launch(void* const* d_in, const int* in_sizes, int n_in,
                              void* d_out, int out_size, void* d_ws, size_t ws_size,
                              hipStream_t stream)
{
    const float* x  = (const float*)d_in[0];
    const float* gw = (const float*)d_in[1];
    const float* w1 = (const float*)d_in[2];
    const float* b1 = (const float*)d_in[3];
    const float* w2 = (const float*)d_in[4];
    const float* b2 = (const float*)d_in[5];
    float* out = (float*)d_out;

    char* ws = (char*)d_ws;
    int*   counts  = (int*)ws;                   // 0
    float* imp     = (float*)(ws + 64);
    int*   offs    = (int*)(ws + 128);           // 9 ints
    int*   tc      = (int*)(ws + 256);           // 8192 ints -> ends 33024
    int*   wl      = (int*)(ws + 33024);         // 136 ints -> 33568
    int*   tokpair = (int*)(ws + 33792);         // 16384 ints -> 99328
    int*   ptok    = (int*)(ws + 99840);
    float* pw      = (float*)(ws + 99840 + (size_t)NE * T_TOK * 4);
    size_t cur = 99840 + (size_t)NE * T_TOK * 8;
    cur = (cur + 511) & ~(size_t)511;

    unsigned short* xg = (unsigned short*)(ws + cur);   // 33.5 MB
    cur += (size_t)2 * T_TOK * DM * 2;
    cur = (cur + 511) & ~(size_t)511;
    float* yv = (float*)(ws + cur);                     // 67 MB
    cur += (size_t)2 * T_TOK * DM * 4;

    const size_t wfull_bytes = (size_t)NE * DFF * DM * 2;
    const size_t hrow_total  = 2 * (size_t)T_TOK;

    int FFC = 0, wfull = 0;
    unsigned short *w1b = nullptr, *w2b = nullptr, *H = nullptr;
    for (int f = DFF; f >= 256; f >>= 1) {
        size_t need = cur + 2 * wfull_bytes + hrow_total * (size_t)f * 2;
        if (need <= ws_size) { FFC = f; wfull = 1; break; }
    }
    if (wfull) {
        w1b = (unsigned short*)(ws + cur); cur += wfull_bytes;
        w2b = (unsigned short*)(ws + cur); cur += wfull_bytes;
        H   = (unsigned short*)(ws + cur);
    } else {
        for (int f = 2048; f >= 256; f >>= 1) {
            size_t wc = (size_t)NE * f * DM * 2;
            size_t need = cur + 2 * wc + hrow_total * (size_t)f * 2;
            if (need <= ws_size) { FFC = f; break; }
        }
        if (FFC == 0) return;
        size_t wc = (size_t)NE * FFC * DM * 2;
        w1b = (unsigned short*)(ws + cur); cur += wc;
        w2b = (unsigned short*)(ws + cur); cur += wc;
        H   = (unsigned short*)(ws + cur);
    }

    hipMemsetAsync(ws, 0, 33024, stream);   // counts/imp/offs + tc

    router_kernel<<<T_TOK / 4, 256, 0, stream>>>(x, gw, counts, imp, ptok, pw);
    finalize_kernel<<<1, 64, 0, stream>>>(counts, imp, offs, wl, out + (size_t)out_size - 1);
    {
        dim3 gp(T_TOK / 4, NE);
        pregather_kernel<<<gp, 256, 0, stream>>>(x, counts, offs, ptok, xg, tc, tokpair);
    }
    if (wfull) {
        long long n = (long long)NE * DFF * DM;
        conv_flat<<<(unsigned)(n / 1024), 256, 0, stream>>>(w1, w1b, n);
        conv_flat<<<(unsigned)(n / 1024), 256, 0, stream>>>(w2, w2b, n);
    }

    const int NCH = DFF / FFC;
    for (int c = 0; c < NCH; ++c) {
        if (!wfull) {
            dim3 gc1((unsigned)((long long)FFC * DM / 1024), NE);
            conv_rows<<<gc1, 256, 0, stream>>>(w1, w1b,
                (long long)c * FFC * DM, (long long)DFF * DM, FFC * DM);
            dim3 gc2((unsigned)((FFC + 1023) / 1024), NE * DM);
            conv_rows<<<gc2, 256, 0, stream>>>(w2, w2b,
                (long long)c * FFC, (long long)DFF, FFC);
        }
        dim3 g1(WLMAX, FFC / 256, 1);
        gemm_bt<0><<<g1, 256, 0, stream>>>(xg, w1b, b1, counts, offs, ptok, pw, wl, H, yv, FFC, c, wfull);
        dim3 g2(WLMAX, DM / 256, 1);
        gemm_bt<1><<<g2, 256, 0, stream>>>(H, w2b, b2, counts, offs, ptok, pw, wl, H, yv, FFC, c, wfull);
    }
    combine_kernel<<<T_TOK, 256, 0, stream>>>(yv, tokpair, out);
}